// Round 11
// baseline (726.919 us; speedup 1.0000x reference)
//
#include <hip/hip_runtime.h>

#define NP 131072   // points (= 2^17, label packs above bit 17)
#define DD 128      // dims (GEMM K)
#define KK 256      // clusters (GEMM N)
#define MAXIT 8
#define TOLSQ (1e-4f * 1e-4f)
#define POSB 256    // positions per k_sum block
#define UPIPE 8     // gather pipeline depth

typedef _Float16 half8 __attribute__((ext_vector_type(8)));
typedef float f32x4 __attribute__((ext_vector_type(4)));

// Async 16B global -> LDS DMA. ldsptr must be the WAVE-UNIFORM base; HW
// writes base + lane*16 (m97/m104 semantics). Our layouts are exactly
// lane-contiguous in fragment order.
__device__ __forceinline__ void async_copy16(const void* g, void* l) {
    __builtin_amdgcn_global_load_lds(
        (const __attribute__((address_space(1))) void*)g,
        (__attribute__((address_space(3))) void*)l, 16, 0, 0);
}

// ws re-poisoned 0xAA before every timed call — every field below is written
// before it is read on every kernel_launch.
struct Ws {
    float C[KK * DD];
    float newC[KK * DD];
    float cnorm[KK];
    float sums[KK * DD];       // per-cluster coordinate sums (atomic-flushed)
    float shiftsq;
    int done;
    int ilab[NP];              // labels
    int counts[KK];            // per-cluster sizes (exact, int)
    int cursor[KK];            // global reservation cursors (zeroed per iter)
    int ordlab[NP];            // cluster-sorted: point | (label<<17)
    // fp16 hi/lo planes, pre-swizzled into MFMA fragment order (16B aligned)
    alignas(16) _Float16 Csh[KK * DD];
    alignas(16) _Float16 Csl[KK * DD];
    alignas(16) _Float16 Xsh[(size_t)NP * DD];
    alignas(16) _Float16 Xsl[(size_t)NP * DD];
};

// C0 = X[init_idx]; zero done flag.  grid: KK x DD
__global__ void k_init(const float* __restrict__ X, const int* __restrict__ idx,
                       float* __restrict__ C, int* __restrict__ done) {
    int k = blockIdx.x, d = threadIdx.x;
    C[k * DD + d] = X[(size_t)idx[k] * DD + d];
    if (k == 0 && d == 0) *done = 0;
}

// Once per call: split X into fp16 hi/lo planes in A-fragment order.
// A-frag (16x16x32 f16): lane L of the wave owning 16-point group g16 at
// k-step ks holds X[g16*16 + (L&15)][ks*32 + (L>>4)*8 + j], j=0..7.
// Flat: Xs[(((g16*4)+ks)*64 + L)*8 + j].  grid: NP*DD/8/256 = 8192 blocks.
__global__ void k_split(const float* __restrict__ X, _Float16* __restrict__ Xh,
                        _Float16* __restrict__ Xl) {
    size_t idx = (size_t)blockIdx.x * 256 + threadIdx.x;  // one per 8 elems
    int lane = idx & 63;
    size_t g16k = idx >> 6;
    size_t point = (g16k >> 2) * 16 + (lane & 15);
    int dim0 = (int)(g16k & 3) * 32 + (lane >> 4) * 8;
    const f32x4* s4 = (const f32x4*)(X + point * DD + dim0);
    f32x4 a = s4[0], b = s4[1];
    half8 h, l;
#pragma unroll
    for (int j = 0; j < 4; j++) {
        _Float16 hi = (_Float16)a[j];
        h[j] = hi; l[j] = (_Float16)(a[j] - (float)hi);
    }
#pragma unroll
    for (int j = 0; j < 4; j++) {
        _Float16 hi = (_Float16)b[j];
        h[4 + j] = hi; l[4 + j] = (_Float16)(b[j] - (float)hi);
    }
    *(half8*)(Xh + idx * 8) = h;
    *(half8*)(Xl + idx * 8) = l;
}

// Initial prep: cnorm + hi/lo B-fragment planes for C0; zero counts/cursor.
// B-frag: lane L at (ks, cluster-tile ct) holds C[ct*16+(L&15)][ks*32+(L>>4)*8+j]
// -> flat ((ks*16+ct)*64 + L)*8 + j.  grid: KK x DD
__global__ void k_prep0(const float* __restrict__ C, float* __restrict__ cnorm,
                        _Float16* __restrict__ Ch, _Float16* __restrict__ Cl,
                        int* __restrict__ counts, int* __restrict__ cursor) {
    int k = blockIdx.x, d = threadIdx.x;
    float v = C[k * DD + d];
    _Float16 hi = (_Float16)v;
    int ct = k >> 4, l4 = k & 15, ks = d >> 5, q = (d >> 3) & 3, j = d & 7;
    size_t dst = ((size_t)(ks * 16 + ct) * 64 + (q * 16 + l4)) * 8 + j;
    Ch[dst] = hi;
    Cl[dst] = (_Float16)(v - (float)hi);
    __shared__ float red[DD];
    red[d] = v * v;
    __syncthreads();
    for (int s = DD / 2; s > 0; s >>= 1) {
        if (d < s) red[d] += red[d + s];
        __syncthreads();
    }
    if (d == 0) {
        cnorm[k] = red[0];
        counts[k] = 0;
        cursor[k] = 0;
    }
}

// MFMA assignment. Double-buffered LDS B + REGISTER-PREFETCHED A: A(ks+1) is
// issued at the top of iter ks but used only AFTER the barrier — so compute(ks)
// starts with zero VMEM waits (its A regs were drained at the previous
// barrier). R10's flaw: A issued after the stage DMAs meant waiting for A
// forced vmcnt(0), draining the prefetch — in-order vmcnt defeated the dbuf.
// Epilogue: NaN hoisted out (empty cluster -> all-NaN s-column -> every point
// gets first-NaN index, detected once per wave from cnorm), leaving a plain
// (s,k) float argmin with np tie-break semantics.
// Registers: acc 128 (AGPR) + 2x16 A + misc < 256 -> 2 waves/SIMD, no spill.
// LDS: 2 x 32 KB + hist = 65.5 KB -> 2 blocks/CU. grid: NP/128 x 256.
__global__ __launch_bounds__(256, 2) void k_assign(
    const _Float16* __restrict__ Xh, const _Float16* __restrict__ Xl,
    const _Float16* __restrict__ Ch, const _Float16* __restrict__ Cl,
    const float* __restrict__ cnorm, float* __restrict__ outlab,
    int* __restrict__ ilab, int* __restrict__ counts,
    float* __restrict__ shiftsq) {
    __shared__ __align__(16) _Float16 Bls[2 * 2 * 16 * 64 * 8];  // 2 bufs x 32 KB
    __shared__ int hist[KK];
    if (blockIdx.x == 0 && threadIdx.x == 0) *shiftsq = 0.0f;
    hist[threadIdx.x] = 0;

    const int wave = threadIdx.x >> 6;
    const int lane = threadIdx.x & 63;
    const int l4 = lane & 15, g = lane >> 4;
    const int g16 = blockIdx.x * 8 + wave * 2;
    char* const lds = (char*)Bls;

    // Stage one 32 KB slice (Ch half + Cl half) into buffer `buf`.
    auto stage = [&](int ks, int buf) {
        char* dst = lds + buf * 32768;
#pragma unroll
        for (int j = 0; j < 4; j++) {
            const int slot = j * 256 + wave * 64;  // 16B units within plane
            async_copy16(Ch + (size_t)ks * 8192 + (size_t)(slot + lane) * 8,
                         dst + (size_t)slot * 16);
            async_copy16(Cl + (size_t)ks * 8192 + (size_t)(slot + lane) * 8,
                         dst + 16384 + (size_t)slot * 16);
        }
    };

    f32x4 acc[2][16];
#pragma unroll
    for (int pg = 0; pg < 2; pg++)
#pragma unroll
        for (int ct = 0; ct < 16; ct++) acc[pg][ct] = (f32x4){0.f, 0.f, 0.f, 0.f};

    // Prologue: A(0) regs + stage(0); the one exposed drain.
    const size_t p0 = ((size_t)(g16 * 4) * 64 + lane) * 8;
    const size_t p1 = ((size_t)((g16 + 1) * 4) * 64 + lane) * 8;
    half8 cah0 = *(const half8*)(Xh + p0);
    half8 cal0 = *(const half8*)(Xl + p0);
    half8 cah1 = *(const half8*)(Xh + p1);
    half8 cal1 = *(const half8*)(Xl + p1);
    stage(0, 0);
    __syncthreads();

#pragma unroll 1
    for (int ks = 0; ks < 4; ks++) {
        // Prefetch A(ks+1) + stage(ks+1): consumed only after the barrier
        // below, so compute(ks) never waits on them.
        half8 nah0, nal0, nah1, nal1;
        if (ks < 3) {
            const size_t b0 = ((size_t)(g16 * 4 + ks + 1) * 64 + lane) * 8;
            const size_t b1 = ((size_t)((g16 + 1) * 4 + ks + 1) * 64 + lane) * 8;
            nah0 = *(const half8*)(Xh + b0);
            nal0 = *(const half8*)(Xl + b0);
            nah1 = *(const half8*)(Xh + b1);
            nal1 = *(const half8*)(Xl + b1);
            stage(ks + 1, (ks + 1) & 1);
        } else {
            nah0 = cah0; nal0 = cal0; nah1 = cah1; nal1 = cal1;
        }

        char* cur = lds + (ks & 1) * 32768;
#pragma unroll
        for (int ct = 0; ct < 16; ct++) {
            half8 bh = *(const half8*)(cur + ct * 1024 + lane * 16);
            half8 bl = *(const half8*)(cur + 16384 + ct * 1024 + lane * 16);
            acc[0][ct] = __builtin_amdgcn_mfma_f32_16x16x32_f16(cal0, bh, acc[0][ct], 0, 0, 0);
            acc[0][ct] = __builtin_amdgcn_mfma_f32_16x16x32_f16(cah0, bl, acc[0][ct], 0, 0, 0);
            acc[0][ct] = __builtin_amdgcn_mfma_f32_16x16x32_f16(cah0, bh, acc[0][ct], 0, 0, 0);
            acc[1][ct] = __builtin_amdgcn_mfma_f32_16x16x32_f16(cal1, bh, acc[1][ct], 0, 0, 0);
            acc[1][ct] = __builtin_amdgcn_mfma_f32_16x16x32_f16(cah1, bl, acc[1][ct], 0, 0, 0);
            acc[1][ct] = __builtin_amdgcn_mfma_f32_16x16x32_f16(cah1, bh, acc[1][ct], 0, 0, 0);
        }
        __syncthreads();  // drains A(ks+1)+DMA(ks+1) AFTER compute covered them
        cah0 = nah0; cal0 = nal0; cah1 = nah1; cal1 = nal1;
    }

    float cn[16];
#pragma unroll
    for (int ct = 0; ct < 16; ct++) cn[ct] = cnorm[ct * 16 + l4];

    // Empty-cluster NaN handling hoisted out of the hot loop: a NaN centroid
    // makes its whole s-column NaN, so np.argmin returns the FIRST NaN index
    // for every point. Detect once per wave from cnorm.
    int nank = 0x7fffffff;
#pragma unroll
    for (int ct = 15; ct >= 0; ct--)
        if (__builtin_isnan(cn[ct])) nank = ct * 16 + l4;
#pragma unroll
    for (int d = 1; d < 16; d <<= 1) {
        int o = __shfl_xor(nank, d, 64);
        nank = nank < o ? nank : o;
    }

    // Plain (s,k) argmin. No NaNs possible here (finite inputs, fp32 range).
    // Ascending-ct strict < keeps the first (lowest-k) minimum per lane.
    float bs[2][4];
    int bk[2][4];
#pragma unroll
    for (int pg = 0; pg < 2; pg++)
#pragma unroll
        for (int r = 0; r < 4; r++) {
            bs[pg][r] = fmaf(-2.0f, acc[pg][0][r], cn[0]);
            bk[pg][r] = l4;
        }
#pragma unroll
    for (int ct = 1; ct < 16; ct++)
#pragma unroll
        for (int pg = 0; pg < 2; pg++)
#pragma unroll
            for (int r = 0; r < 4; r++) {
                float s = fmaf(-2.0f, acc[pg][ct][r], cn[ct]);
                if (s < bs[pg][r]) {
                    bs[pg][r] = s;
                    bk[pg][r] = ct * 16 + l4;
                }
            }

    // Cross-lane reduce over the 16 cluster-column lanes; equal-s tie -> lower
    // k (np first-index semantics).
#pragma unroll
    for (int d = 1; d < 16; d <<= 1)
#pragma unroll
        for (int pg = 0; pg < 2; pg++)
#pragma unroll
            for (int r = 0; r < 4; r++) {
                float os = __shfl_xor(bs[pg][r], d, 64);
                int ok = __shfl_xor(bk[pg][r], d, 64);
                bool take = (os < bs[pg][r]) ||
                            (os == bs[pg][r] && ok < bk[pg][r]);
                if (take) {
                    bs[pg][r] = os;
                    bk[pg][r] = ok;
                }
            }

    __syncthreads();  // hist zeros visible (ordered by loop barriers too)
    if (l4 == 0) {
#pragma unroll
        for (int pg = 0; pg < 2; pg++)
#pragma unroll
            for (int r = 0; r < 4; r++) {
                int point = blockIdx.x * 128 + wave * 32 + pg * 16 + g * 4 + r;
                int lbl = (nank != 0x7fffffff) ? nank : bk[pg][r];
                outlab[point] = (float)lbl;
                ilab[point] = lbl;
                atomicAdd(&hist[lbl], 1);
            }
    }
    __syncthreads();
    int h = hist[threadIdx.x];
    if (h) atomicAdd(&counts[threadIdx.x], h);
}

// Counting-sort scatter. Block = 512 points: LDS histogram, redundant prefix
// of global counts, ONE block-aggregated cursor reservation per cluster, then
// rank & write ordlab[pos] = p | (label<<17). Also zeroes sums for k_sum.
// grid: NP/512 = 256 blocks x 256 threads.
__global__ __launch_bounds__(256) void k_scatter(
    const int* __restrict__ ilab, const int* __restrict__ counts,
    int* __restrict__ cursor, int* __restrict__ ordlab,
    float* __restrict__ sums) {
    const int t = threadIdx.x;
    const int b = blockIdx.x;

    // zero sums slice: 256 blocks x 128 floats = KK*DD
    if (t < 128) sums[b * 128 + t] = 0.0f;

    __shared__ int hist[KK];
    __shared__ int pre[KK];
    __shared__ int gbase[KK];
    hist[t] = 0;
    int c = counts[t];
    pre[t] = c;
    __syncthreads();

    const int p0 = b * 512;
    const int la = ilab[p0 + t];
    const int lb = ilab[p0 + 256 + t];
    atomicAdd(&hist[la], 1);
    atomicAdd(&hist[lb], 1);

    // inclusive prefix of counts (Hillis-Steele)
#pragma unroll
    for (int d = 1; d < KK; d <<= 1) {
        int v = (t >= d) ? pre[t - d] : 0;
        __syncthreads();
        pre[t] += v;
        __syncthreads();
    }
    // after these syncs all hist atomics are complete
    int h = hist[t];
    int gb = (pre[t] - c) + (h ? atomicAdd(&cursor[t], h) : 0);
    gbase[t] = gb;
    __syncthreads();
    hist[t] = 0;  // reuse as intra-block rank cursor
    __syncthreads();

    int ra = atomicAdd(&hist[la], 1);
    ordlab[gbase[la] + ra] = (p0 + t) | (la << 17);
    int rb = atomicAdd(&hist[lb], 1);
    ordlab[gbase[lb] + rb] = (p0 + 256 + t) | (lb << 17);
}

// Streaming segmented sum over the cluster-sorted position list.
// Position-balanced (immune to cluster-size skew). Thread = (dim d, parity h);
// U-deep double-buffered row gathers; register accumulator flushed on label
// change (wave-uniform branch) via coalesced global atomicAdd — few per block.
// grid: NP/POSB = 512 blocks x 256 threads.
__global__ __launch_bounds__(256) void k_sum(
    const float* __restrict__ X, const int* __restrict__ ordlab,
    float* __restrict__ sums) {
    const int t = threadIdx.x;
    const int d = t & 127, h = t >> 7;

    __shared__ int sol[POSB];
    sol[t] = ordlab[blockIdx.x * POSB + t];
    __syncthreads();

    const int PP = POSB / 2;  // positions per parity
    float xv[UPIPE], xn[UPIPE];
#pragma unroll
    for (int u = 0; u < UPIPE; u++)
        xv[u] = X[(size_t)(sol[2 * u + h] & 0x1ffff) * DD + d];

    float acc = 0.0f;
    int cur = sol[h] >> 17;

    for (int jb = 0; jb < PP; jb += UPIPE) {
        // issue next batch's gathers (tail clamped to a harmless valid index)
#pragma unroll
        for (int u = 0; u < UPIPE; u++) {
            int nj = jb + u + UPIPE;
            int o = sol[2 * (nj < PP ? nj : PP - 1) + h];
            xn[u] = X[(size_t)(o & 0x1ffff) * DD + d];
        }
        // consume current batch
#pragma unroll
        for (int u = 0; u < UPIPE; u++) {
            int l = sol[2 * (jb + u) + h] >> 17;
            if (l != cur) {
                atomicAdd(&sums[cur * DD + d], acc);
                acc = 0.0f;
                cur = l;
            }
            acc += xv[u];
        }
#pragma unroll
        for (int u = 0; u < UPIPE; u++) xv[u] = xn[u];
    }
    atomicAdd(&sums[cur * DD + d], acc);
}

// newC = sums/counts (0/0 -> NaN, matching jnp); shift^2 block-reduced,
// one atomic per block.  grid: KK*DD/256 x 256
__global__ void k_reduce(const float* __restrict__ sums, const int* __restrict__ counts,
                         const float* __restrict__ C, float* __restrict__ newC,
                         float* __restrict__ shiftsq) {
    const int g = blockIdx.x * 256 + threadIdx.x;
    const int k = g >> 7;
    const int t = threadIdx.x;

    float nc = sums[g] / (float)counts[k];
    newC[g] = nc;
    float diff = nc - C[g];

    __shared__ float red[256];
    red[t] = diff * diff;
    __syncthreads();
    for (int st = 128; st > 0; st >>= 1) {
        if (t < st) red[t] += red[t + st];
        __syncthreads();
    }
    if (t == 0) atomicAdd(shiftsq, red[0]);
}

// Fused convergence check + centroid update + next-iter prep (cnorm + hi/lo
// planes) + zero counts/cursor. NaN shiftsq -> not converged (jnp match).
// Benign done race: all blocks compute the same nd.  grid: KK/2 x 256.
__global__ void k_upprep(const float* __restrict__ newC, float* __restrict__ C,
                         const float* __restrict__ shiftsq, int* __restrict__ done,
                         float* __restrict__ cnorm, _Float16* __restrict__ Ch,
                         _Float16* __restrict__ Cl, int* __restrict__ counts,
                         int* __restrict__ cursor) {
    const int t = threadIdx.x;
    const int k = blockIdx.x * 2 + (t >> 7);
    const int d = t & 127;
    float ss = *shiftsq;
    int nd = (*done != 0) || (ss < TOLSQ);
    float v = nd ? C[k * DD + d] : newC[k * DD + d];
    C[k * DD + d] = v;
    if (blockIdx.x == 0 && t == 0 && nd) *done = 1;
    if (d == 0) {
        counts[k] = 0;
        cursor[k] = 0;
    }

    _Float16 hi = (_Float16)v;
    int ct = k >> 4, l4 = k & 15, ks = d >> 5, q = (d >> 3) & 3, j = d & 7;
    size_t dst = ((size_t)(ks * 16 + ct) * 64 + (q * 16 + l4)) * 8 + j;
    Ch[dst] = hi;
    Cl[dst] = (_Float16)(v - (float)hi);

    __shared__ float red[256];
    red[t] = v * v;
    __syncthreads();
    for (int s = 64; s > 0; s >>= 1) {
        if ((t & 127) < s) red[t] += red[t + s];
        __syncthreads();
    }
    if (d == 0) cnorm[k] = red[t];
}

__global__ void k_final(const float* __restrict__ C, float* __restrict__ out) {
    int i = blockIdx.x * 256 + threadIdx.x;
    out[i] = C[i];
}

extern "C" void kernel_launch(void* const* d_in, const int* in_sizes, int n_in,
                              void* d_out, int out_size, void* d_ws, size_t ws_size,
                              hipStream_t stream) {
    const float* X = (const float*)d_in[0];
    const int* idx = (const int*)d_in[1];
    float* out = (float*)d_out;
    Ws* w = (Ws*)d_ws;

    k_init<<<KK, DD, 0, stream>>>(X, idx, w->C, &w->done);
    k_split<<<(int)((size_t)NP * DD / 8 / 256), 256, 0, stream>>>(X, w->Xsh, w->Xsl);
    k_prep0<<<KK, DD, 0, stream>>>(w->C, w->cnorm, w->Csh, w->Csl, w->counts, w->cursor);

    for (int it = 0; it < MAXIT; it++) {
        k_assign<<<NP / 128, 256, 0, stream>>>(w->Xsh, w->Xsl, w->Csh, w->Csl,
                                               w->cnorm, out, w->ilab, w->counts,
                                               &w->shiftsq);
        k_scatter<<<NP / 512, 256, 0, stream>>>(w->ilab, w->counts, w->cursor,
                                                w->ordlab, w->sums);
        k_sum<<<NP / POSB, 256, 0, stream>>>(X, w->ordlab, w->sums);
        k_reduce<<<KK * DD / 256, 256, 0, stream>>>(w->sums, w->counts, w->C,
                                                    w->newC, &w->shiftsq);
        k_upprep<<<KK / 2, 256, 0, stream>>>(w->newC, w->C, &w->shiftsq, &w->done,
                                             w->cnorm, w->Csh, w->Csl, w->counts,
                                             w->cursor);
    }

    k_final<<<KK * DD / 256, 256, 0, stream>>>(w->C, out + NP);
}